// Round 1
// baseline (539.850 us; speedup 1.0000x reference)
//
#include <hip/hip_runtime.h>
#include <math.h>

// Problem constants (match reference)
#define BB 32
#define SS 2048
#define DD 1024
#define BETA_C 0.1f
#define RHO_C 1.0f

#define CHUNKS 64   // chunks per batch -> 32*64 = 2048 blocks
#define TPB 256

// Per-batch dot products: lp[b] = sum_{s,d} e1[b,s,d]*w[d]; lp[B+b] same for e2.
// Memory-bound: one coalesced float4 pass over both tensors.
__global__ __launch_bounds__(TPB) void dot_kernel(
    const float* __restrict__ e1, const float* __restrict__ e2,
    const float* __restrict__ w, float* __restrict__ lp)
{
    __shared__ float4 w4s[DD / 4];           // 4 KB: w staged in LDS
    for (int i = threadIdx.x; i < DD / 4; i += TPB)
        w4s[i] = ((const float4*)w)[i];
    __syncthreads();

    const int b     = blockIdx.x & (BB - 1);   // batch
    const int chunk = blockIdx.x >> 5;         // chunk within batch (BB=32)
    const long long batchBase = (long long)b * (SS * DD);
    const int vecPerChunk = (SS * DD / 4) / CHUNKS;   // 8192 float4 per chunk
    const int vstart = chunk * vecPerChunk;

    const float4* e1v = (const float4*)(e1 + batchBase);
    const float4* e2v = (const float4*)(e2 + batchBase);

    float s1 = 0.f, s2 = 0.f;
    for (int v = vstart + (int)threadIdx.x; v < vstart + vecPerChunk; v += TPB) {
        const float4 wv = w4s[v & (DD / 4 - 1)];  // d index = (4v) % D
        const float4 a  = e1v[v];
        const float4 c  = e2v[v];
        s1 += a.x * wv.x + a.y * wv.y + a.z * wv.z + a.w * wv.w;
        s2 += c.x * wv.x + c.y * wv.y + c.z * wv.z + c.w * wv.w;
    }

    // wave (64-lane) reduction
    #pragma unroll
    for (int off = 32; off > 0; off >>= 1) {
        s1 += __shfl_down(s1, off, 64);
        s2 += __shfl_down(s2, off, 64);
    }
    __shared__ float red1[TPB / 64], red2[TPB / 64];
    const int lane = threadIdx.x & 63;
    const int wid  = threadIdx.x >> 6;
    if (lane == 0) { red1[wid] = s1; red2[wid] = s2; }
    __syncthreads();
    if (threadIdx.x == 0) {
        float t1 = 0.f, t2 = 0.f;
        #pragma unroll
        for (int i = 0; i < TPB / 64; i++) { t1 += red1[i]; t2 += red2[i]; }
        atomicAdd(&lp[b], t1);          // device-scope by default on CDNA
        atomicAdd(&lp[BB + b], t2);
    }
}

__device__ __forceinline__ float log_sigmoid(float x) {
    // stable: min(x,0) - log1p(exp(-|x|))
    return fminf(x, 0.f) - log1pf(expf(-fabsf(x)));
}

// One wave: closed-form loss + grad-norm term.
__global__ void finalize_kernel(
    const float* __restrict__ lp, const float* __restrict__ w,
    const float* __restrict__ lp1ref, const float* __restrict__ lp2ref,
    const float* __restrict__ pref, float* __restrict__ out)
{
    const int lane = threadIdx.x;   // 64 threads
    float sw2 = 0.f;
    for (int i = lane; i < DD; i += 64) { const float x = w[i]; sw2 += x * x; }
    #pragma unroll
    for (int off = 32; off > 0; off >>= 1) sw2 += __shfl_down(sw2, off, 64);
    sw2 = __shfl(sw2, 0, 64);       // broadcast Σ w^2

    float ind = 0.f, gns = 0.f;
    if (lane < BB) {
        const float z = BETA_C * ((lp[lane] - lp1ref[lane]) - (lp[BB + lane] - lp2ref[lane]));
        const float p = pref[lane];
        const float l1 = -log_sigmoid(z);
        const float l2 = -log_sigmoid(-z);
        ind = p * l1 + (1.f - p) * l2;
        const float sig = 1.f / (1.f + expf(-z));
        const float dv  = sig - p;                  // d(ind)/dz
        // grad_norm_sq[b] = 2 * beta^2 * (sig-p)^2 * S * sum(w^2)
        gns = 2.f * BETA_C * BETA_C * (float)SS * sw2 * dv * dv;
    }
    #pragma unroll
    for (int off = 32; off > 0; off >>= 1) {
        ind += __shfl_down(ind, off, 64);
        gns += __shfl_down(gns, off, 64);
    }
    if (lane == 0)
        out[0] = ind / (float)BB + RHO_C * sqrtf(gns / (float)BB);
}

extern "C" void kernel_launch(void* const* d_in, const int* in_sizes, int n_in,
                              void* d_out, int out_size, void* d_ws, size_t ws_size,
                              hipStream_t stream) {
    const float* e1     = (const float*)d_in[0];
    const float* e2     = (const float*)d_in[1];
    const float* w      = (const float*)d_in[2];
    const float* lp1ref = (const float*)d_in[3];
    const float* lp2ref = (const float*)d_in[4];
    const float* pref   = (const float*)d_in[5];
    float* out = (float*)d_out;
    float* lp  = (float*)d_ws;   // lp1[32] then lp2[32]

    hipMemsetAsync(lp, 0, 2 * BB * sizeof(float), stream);
    dot_kernel<<<BB * CHUNKS, TPB, 0, stream>>>(e1, e2, w, lp);
    finalize_kernel<<<1, 64, 0, stream>>>(lp, w, lp1ref, lp2ref, pref, out);
}

// Round 2
// 522.776 us; speedup vs baseline: 1.0327x; 1.0327x over previous
//
#include <hip/hip_runtime.h>
#include <math.h>

// Problem constants (match reference)
#define BB 32
#define SS 2048
#define DD 1024
#define BETA_C 0.1f
#define RHO_C 1.0f

#define CHUNKS 64   // chunks per batch -> 32*64 = 2048 blocks
#define TPB 256
#define ITERS ((SS * DD / 4) / CHUNKS / TPB)   // 32 float4-loads per thread per tensor

// Per-batch dot products: lp[b] = sum_{s,d} e1[b,s,d]*w[d]; lp[B+b] same for e2.
// Memory-latency-aware: v = vstart + tid + k*256 with vstart % 256 == 0, so each
// thread's w index is constant (== tid): hoist w out of the loop, 4-way unroll
// for 8 outstanding 16B global loads per thread.
__global__ __launch_bounds__(TPB) void dot_kernel(
    const float* __restrict__ e1, const float* __restrict__ e2,
    const float* __restrict__ w, float* __restrict__ lp)
{
    const int tid   = threadIdx.x;
    const int b     = blockIdx.x & (BB - 1);   // batch
    const int chunk = blockIdx.x >> 5;         // chunk within batch (BB=32)
    const long long batchBase = (long long)b * (SS * DD);
    const int vstart = chunk * (TPB * ITERS);  // multiple of 256

    const float4 wv = ((const float4*)w)[tid];  // constant for this thread's whole loop

    const float4* e1v = (const float4*)(e1 + batchBase) + vstart + tid;
    const float4* e2v = (const float4*)(e2 + batchBase) + vstart + tid;

    float s1a = 0.f, s1b = 0.f, s1c = 0.f, s1d = 0.f;
    float s2a = 0.f, s2b = 0.f, s2c = 0.f, s2d = 0.f;
    #pragma unroll
    for (int k = 0; k < ITERS; k += 4) {
        const float4 a0 = e1v[(k + 0) * TPB];
        const float4 a1 = e1v[(k + 1) * TPB];
        const float4 a2 = e1v[(k + 2) * TPB];
        const float4 a3 = e1v[(k + 3) * TPB];
        const float4 c0 = e2v[(k + 0) * TPB];
        const float4 c1 = e2v[(k + 1) * TPB];
        const float4 c2 = e2v[(k + 2) * TPB];
        const float4 c3 = e2v[(k + 3) * TPB];
        s1a += a0.x * wv.x + a0.y * wv.y + a0.z * wv.z + a0.w * wv.w;
        s1b += a1.x * wv.x + a1.y * wv.y + a1.z * wv.z + a1.w * wv.w;
        s1c += a2.x * wv.x + a2.y * wv.y + a2.z * wv.z + a2.w * wv.w;
        s1d += a3.x * wv.x + a3.y * wv.y + a3.z * wv.z + a3.w * wv.w;
        s2a += c0.x * wv.x + c0.y * wv.y + c0.z * wv.z + c0.w * wv.w;
        s2b += c1.x * wv.x + c1.y * wv.y + c1.z * wv.z + c1.w * wv.w;
        s2c += c2.x * wv.x + c2.y * wv.y + c2.z * wv.z + c2.w * wv.w;
        s2d += c3.x * wv.x + c3.y * wv.y + c3.z * wv.z + c3.w * wv.w;
    }
    float s1 = (s1a + s1b) + (s1c + s1d);
    float s2 = (s2a + s2b) + (s2c + s2d);

    // wave (64-lane) reduction
    #pragma unroll
    for (int off = 32; off > 0; off >>= 1) {
        s1 += __shfl_down(s1, off, 64);
        s2 += __shfl_down(s2, off, 64);
    }
    __shared__ float red1[TPB / 64], red2[TPB / 64];
    const int lane = tid & 63;
    const int wid  = tid >> 6;
    if (lane == 0) { red1[wid] = s1; red2[wid] = s2; }
    __syncthreads();
    if (tid == 0) {
        float t1 = 0.f, t2 = 0.f;
        #pragma unroll
        for (int i = 0; i < TPB / 64; i++) { t1 += red1[i]; t2 += red2[i]; }
        atomicAdd(&lp[b], t1);          // device-scope by default on CDNA
        atomicAdd(&lp[BB + b], t2);
    }
}

__device__ __forceinline__ float log_sigmoid(float x) {
    // stable: min(x,0) - log1p(exp(-|x|))
    return fminf(x, 0.f) - log1pf(expf(-fabsf(x)));
}

// One wave: closed-form loss + grad-norm term.
// grad wrt embeddings is rank-1: g1[b,s,d] = beta*(sigma(z_b)-p_b)*w[d], g2 = -g1
// => grad_norm_sq[b] = 2*beta^2*(sigma(z_b)-p_b)^2 * S * sum(w^2)
__global__ void finalize_kernel(
    const float* __restrict__ lp, const float* __restrict__ w,
    const float* __restrict__ lp1ref, const float* __restrict__ lp2ref,
    const float* __restrict__ pref, float* __restrict__ out)
{
    const int lane = threadIdx.x;   // 64 threads
    float sw2 = 0.f;
    for (int i = lane; i < DD; i += 64) { const float x = w[i]; sw2 += x * x; }
    #pragma unroll
    for (int off = 32; off > 0; off >>= 1) sw2 += __shfl_down(sw2, off, 64);
    sw2 = __shfl(sw2, 0, 64);       // broadcast Σ w^2

    float ind = 0.f, gns = 0.f;
    if (lane < BB) {
        const float z = BETA_C * ((lp[lane] - lp1ref[lane]) - (lp[BB + lane] - lp2ref[lane]));
        const float p = pref[lane];
        const float l1 = -log_sigmoid(z);
        const float l2 = -log_sigmoid(-z);
        ind = p * l1 + (1.f - p) * l2;
        const float sig = 1.f / (1.f + expf(-z));
        const float dv  = sig - p;                  // d(ind)/dz
        gns = 2.f * BETA_C * BETA_C * (float)SS * sw2 * dv * dv;
    }
    #pragma unroll
    for (int off = 32; off > 0; off >>= 1) {
        ind += __shfl_down(ind, off, 64);
        gns += __shfl_down(gns, off, 64);
    }
    if (lane == 0)
        out[0] = ind / (float)BB + RHO_C * sqrtf(gns / (float)BB);
}

extern "C" void kernel_launch(void* const* d_in, const int* in_sizes, int n_in,
                              void* d_out, int out_size, void* d_ws, size_t ws_size,
                              hipStream_t stream) {
    const float* e1     = (const float*)d_in[0];
    const float* e2     = (const float*)d_in[1];
    const float* w      = (const float*)d_in[2];
    const float* lp1ref = (const float*)d_in[3];
    const float* lp2ref = (const float*)d_in[4];
    const float* pref   = (const float*)d_in[5];
    float* out = (float*)d_out;
    float* lp  = (float*)d_ws;   // lp1[32] then lp2[32]

    hipMemsetAsync(lp, 0, 2 * BB * sizeof(float), stream);
    dot_kernel<<<BB * CHUNKS, TPB, 0, stream>>>(e1, e2, w, lp);
    finalize_kernel<<<1, 64, 0, stream>>>(lp, w, lp1ref, lp2ref, pref, out);
}

// Round 3
// 517.637 us; speedup vs baseline: 1.0429x; 1.0099x over previous
//
#include <hip/hip_runtime.h>
#include <math.h>

// Problem constants (match reference)
#define BB 32
#define SS 2048
#define DD 1024
#define BETA_C 0.1f
#define RHO_C 1.0f

#define TPB 256
#define NBLK_PER_T 512        // blocks per tensor; grid = 1024 (4 blocks/CU)
// per block: 512 KB = 32768 float4; per wave: contiguous 128 KB = 8192 float4;
// per lane: 128 float4 loads, stepping 64 vecs (1 KB wave-contiguous granules)

__device__ __forceinline__ float dot4(float4 a, float4 b) {
    return a.x * b.x + a.y * b.y + a.z * b.z + a.w * b.w;
}

// lp[t*BB + b] = sum over e_t[b,:,:] * w (broadcast over S).
// Each block streams one contiguous 512 KB region of ONE tensor: pure
// sequential DRAM streams, 4096 wave-streams total, 8-deep MLP.
__global__ __launch_bounds__(TPB) void dot_kernel(
    const float* __restrict__ e1, const float* __restrict__ e2,
    const float* __restrict__ w, float* __restrict__ lp)
{
    const int t    = blockIdx.x >> 9;          // 0: e1, 1: e2
    const int j    = blockIdx.x & (NBLK_PER_T - 1);
    const int lane = threadIdx.x & 63;
    const int wid  = threadIdx.x >> 6;
    const int batch = j >> 4;                  // 16 blocks per 8 MiB batch row

    const float* e = t ? e2 : e1;
    const float4* w4 = (const float4*)w;       // 256 entries
    // v = j*32768 + wid*8192 + lane + iter*64 ; v mod 256 = (lane + 64*iter) mod 256
    const float4 w0 = w4[lane];
    const float4 w1 = w4[lane + 64];
    const float4 w2 = w4[lane + 128];
    const float4 w3 = w4[lane + 192];

    const float4* p = (const float4*)e + (long long)j * 32768 + wid * 8192 + lane;

    float a0 = 0.f, a1 = 0.f, a2 = 0.f, a3 = 0.f;
    float a4 = 0.f, a5 = 0.f, a6 = 0.f, a7 = 0.f;
    #pragma unroll
    for (int k = 0; k < 128; k += 8) {
        const float4 v0 = p[(k + 0) * 64];
        const float4 v1 = p[(k + 1) * 64];
        const float4 v2 = p[(k + 2) * 64];
        const float4 v3 = p[(k + 3) * 64];
        const float4 v4 = p[(k + 4) * 64];
        const float4 v5 = p[(k + 5) * 64];
        const float4 v6 = p[(k + 6) * 64];
        const float4 v7 = p[(k + 7) * 64];
        a0 += dot4(v0, w0);   // (k+0)&3 == 0
        a1 += dot4(v1, w1);
        a2 += dot4(v2, w2);
        a3 += dot4(v3, w3);
        a4 += dot4(v4, w0);
        a5 += dot4(v5, w1);
        a6 += dot4(v6, w2);
        a7 += dot4(v7, w3);
    }
    float s = ((a0 + a4) + (a1 + a5)) + ((a2 + a6) + (a3 + a7));

    // wave (64-lane) reduction
    #pragma unroll
    for (int off = 32; off > 0; off >>= 1)
        s += __shfl_down(s, off, 64);

    __shared__ float red[TPB / 64];
    if (lane == 0) red[wid] = s;
    __syncthreads();
    if (threadIdx.x == 0) {
        float tot = 0.f;
        #pragma unroll
        for (int i = 0; i < TPB / 64; i++) tot += red[i];
        atomicAdd(&lp[t * BB + batch], tot);   // 16 atomics per address
    }
}

__device__ __forceinline__ float log_sigmoid(float x) {
    // stable: min(x,0) - log1p(exp(-|x|))
    return fminf(x, 0.f) - log1pf(expf(-fabsf(x)));
}

// One wave: closed-form loss + grad-norm term.
// grad wrt embeddings is rank-1: g1[b,s,d] = beta*(sigma(z_b)-p_b)*w[d], g2 = -g1
// => grad_norm_sq[b] = 2*beta^2*(sigma(z_b)-p_b)^2 * S * sum(w^2)
__global__ void finalize_kernel(
    const float* __restrict__ lp, const float* __restrict__ w,
    const float* __restrict__ lp1ref, const float* __restrict__ lp2ref,
    const float* __restrict__ pref, float* __restrict__ out)
{
    const int lane = threadIdx.x;   // 64 threads
    float sw2 = 0.f;
    for (int i = lane; i < DD; i += 64) { const float x = w[i]; sw2 += x * x; }
    #pragma unroll
    for (int off = 32; off > 0; off >>= 1) sw2 += __shfl_down(sw2, off, 64);
    sw2 = __shfl(sw2, 0, 64);       // broadcast sum w^2

    float ind = 0.f, gns = 0.f;
    if (lane < BB) {
        const float z = BETA_C * ((lp[lane] - lp1ref[lane]) - (lp[BB + lane] - lp2ref[lane]));
        const float p = pref[lane];
        const float l1 = -log_sigmoid(z);
        const float l2 = -log_sigmoid(-z);
        ind = p * l1 + (1.f - p) * l2;
        const float sig = 1.f / (1.f + expf(-z));
        const float dv  = sig - p;                  // d(ind)/dz
        gns = 2.f * BETA_C * BETA_C * (float)SS * sw2 * dv * dv;
    }
    #pragma unroll
    for (int off = 32; off > 0; off >>= 1) {
        ind += __shfl_down(ind, off, 64);
        gns += __shfl_down(gns, off, 64);
    }
    if (lane == 0)
        out[0] = ind / (float)BB + RHO_C * sqrtf(gns / (float)BB);
}

extern "C" void kernel_launch(void* const* d_in, const int* in_sizes, int n_in,
                              void* d_out, int out_size, void* d_ws, size_t ws_size,
                              hipStream_t stream) {
    const float* e1     = (const float*)d_in[0];
    const float* e2     = (const float*)d_in[1];
    const float* w      = (const float*)d_in[2];
    const float* lp1ref = (const float*)d_in[3];
    const float* lp2ref = (const float*)d_in[4];
    const float* pref   = (const float*)d_in[5];
    float* out = (float*)d_out;
    float* lp  = (float*)d_ws;   // lp1[32] then lp2[32]

    hipMemsetAsync(lp, 0, 2 * BB * sizeof(float), stream);
    dot_kernel<<<2 * NBLK_PER_T, TPB, 0, stream>>>(e1, e2, w, lp);
    finalize_kernel<<<1, 64, 0, stream>>>(lp, w, lp1ref, lp2ref, pref, out);
}